// Round 13
// baseline (56.237 us; speedup 1.0000x reference)
//
#include <hip/hip_runtime.h>

#define NB 32
#define CC 3
#define HH 512
#define WW 512
#define KS 25
#define PAD 12
#define HT 8                  // output rows per sub-strip
#define LDSW2 268             // words per tile row: 6 halo + 256 + 6 halo (f16 pairs)
#define SUBS 4                // sub-strips per 1024-thread block

typedef __fp16 h2 __attribute__((ext_vector_type(2)));

#if __has_builtin(__builtin_amdgcn_fdot2)
#define FDOT2(a, b, c) __builtin_amdgcn_fdot2((a), (b), (c), false)
#else
#define FDOT2(a, b, c) ((float)(a).x * (float)(b).x + (float)(a).y * (float)(b).y + (c))
#endif

// normalized 1-D gaussian, sigma=9, K=25
__device__ constexpr float Wf[KS] = {
    0.02181520f, 0.02514307f, 0.02862302f, 0.03218484f, 0.03574584f,
    0.03921371f, 0.04249020f, 0.04547544f, 0.04807347f, 0.05019624f,
    0.05176967f, 0.05273727f, 0.05306384f, 0.05273727f, 0.05176967f,
    0.05019624f, 0.04807347f, 0.04547544f, 0.04249020f, 0.03921371f,
    0.03574584f, 0.03218484f, 0.02862302f, 0.02514307f, 0.02181520f};

__device__ constexpr float Wget(int t) {
    return (t >= 0 && t < KS) ? Wf[t] : 0.0f;
}

__device__ __forceinline__ float clamp01(float v) {
    return fminf(fmaxf(v, 0.0f), 1.0f);
}

// Vertical stage for one 8-row sub-strip (256 threads, t in [0,256)).
// EDGE=false: no bounds checks (strips 2..61). NO barrier inside.
template<bool EDGE>
__device__ __forceinline__ void vert_part(const float* __restrict__ ibase,
                                          int r0, int t, unsigned* tile16) {
    // zero halo words: per row, words 0..5 (cols -12..-1) and 262..267
    if (t < HT * 12) {
        int r = t / 12;
        int k = t - r * 12;
        tile16[r * LDSW2 + (k < 6 ? k : 256 + k)] = 0u;
    }
    const float* ip = ibase + t * 2;
    float accx[HT], accy[HT];
#pragma unroll
    for (int j = 0; j < HT; ++j) { accx[j] = 0.f; accy[j] = 0.f; }

#pragma unroll
    for (int k = 0; k < 16; ++k) {               // 16 row pairs = 32 rows
        int rr0 = r0 - PAD + 2 * k;
        int rr1 = rr0 + 1;
        float2 va = make_float2(0.f, 0.f), vb = make_float2(0.f, 0.f);
        if (!EDGE || (rr0 >= 0 && rr0 < HH)) va = *(const float2*)(ip + (long)rr0 * WW);
        if (!EDGE || (rr1 >= 0 && rr1 < HH)) vb = *(const float2*)(ip + (long)rr1 * WW);
        h2 px = __builtin_amdgcn_cvt_pkrtz(va.x, vb.x);
        h2 py = __builtin_amdgcn_cvt_pkrtz(va.y, vb.y);
#pragma unroll
        for (int j = 0; j < HT; ++j) {
            const int t0 = 2 * k - j;            // tap of pair-lo (compile-time)
            if (t0 >= -1 && t0 <= 24) {
                const h2 wp = {(__fp16)Wget(t0), (__fp16)Wget(t0 + 1)};
                accx[j] = FDOT2(px, wp, accx[j]);
                accy[j] = FDOT2(py, wp, accy[j]);
            }
        }
    }
#pragma unroll
    for (int j = 0; j < HT; ++j) {
        h2 w = __builtin_amdgcn_cvt_pkrtz(accx[j], accy[j]);
        tile16[j * LDSW2 + 6 + t] = __builtin_bit_cast(unsigned, w);
    }
}

// Horizontal stage + clip for one sub-strip. NO barrier inside.
__device__ __forceinline__ void horiz_part(float* __restrict__ obase,
                                           int r0, int t, const unsigned* tile16) {
#pragma unroll
    for (int it = 0; it < 2; ++it) {
        int f = it * 256 + t;
        int g = f & 63;                          // lanes -> adjacent col groups
        int row = f >> 6;                        // wave-uniform
        const unsigned* lp = &tile16[row * LDSW2 + 4 * g];
        h2 pa[16];
#pragma unroll
        for (int q = 0; q < 4; ++q) {            // 4x ds_read_b128, 16B stride
            uint4 c = *(const uint4*)(lp + 4 * q);
            pa[4 * q + 0] = __builtin_bit_cast(h2, c.x);
            pa[4 * q + 1] = __builtin_bit_cast(h2, c.y);
            pa[4 * q + 2] = __builtin_bit_cast(h2, c.z);
            pa[4 * q + 3] = __builtin_bit_cast(h2, c.w);
        }
        float res[8];
#pragma unroll
        for (int j = 0; j < 8; ++j) {
            float o = 0.f;
#pragma unroll
            for (int m = 0; m < 16; ++m) {
                const int t0 = 2 * m - j;        // compile-time
                if (t0 >= -1 && t0 <= 24) {
                    const h2 wp = {(__fp16)Wget(t0), (__fp16)Wget(t0 + 1)};
                    o = FDOT2(pa[m], wp, o);
                }
            }
            res[j] = clamp01(o);
        }
        float* op = obase + (long)(r0 + row) * WW + 8 * g;
        *(float4*)(op + 0) = make_float4(res[0], res[1], res[2], res[3]);
        *(float4*)(op + 4) = make_float4(res[4], res[5], res[6], res[7]);
    }
}

// 1024-thread block = 4 independent R11 sub-strips. Tests the hypothesis that
// occupancy (63% at 256-thr blocks with no resource limiter) is capped by
// resident-BLOCK count: 16 waves/block -> 2 blocks reach 32 waves/CU.
// Single kernel-level barrier (all threads reach the same __syncthreads).
__global__ __launch_bounds__(1024, 4) void gblur_fused(const float* __restrict__ x,
                                                       float* __restrict__ out) {
    __shared__ unsigned tile16[SUBS][HT * LDSW2];   // 34,304 B

    int tid = threadIdx.x;
    int sub = tid >> 8;                          // sub-strip 0..3 (4-wave group)
    int t = tid & 255;

    // ---- block mapping with bijective XCD swizzle (1536 % 8 == 0) ----
    int b = blockIdx.x;
    const int nwg = NB * CC * (HH / HT) / SUBS;  // 1536
    int per = nwg >> 3;
    int swz = (b & 7) * per + (b >> 3);
    int plane = swz >> 4;                        // 16 super-strips per plane
    int super = swz & 15;
    int strip = super * SUBS + sub;
    int r0 = strip * HT;

    const float* ibase = x + (long)plane * (HH * WW);
    float*       obase = out + (long)plane * (HH * WW);

    // wave-uniform per sub-strip: strips 2..61 interior
    if (r0 >= PAD && r0 <= HH - HT - PAD)
        vert_part<false>(ibase, r0, t, tile16[sub]);
    else
        vert_part<true>(ibase, r0, t, tile16[sub]);

    __syncthreads();

    horiz_part(obase, r0, t, tile16[sub]);
}

extern "C" void kernel_launch(void* const* d_in, const int* in_sizes, int n_in,
                              void* d_out, int out_size, void* d_ws, size_t ws_size,
                              hipStream_t stream) {
    const float* x = (const float*)d_in[0];
    float* out = (float*)d_out;
    const int nwg = NB * CC * (HH / HT) / SUBS;  // 1536 blocks
    gblur_fused<<<nwg, 1024, 0, stream>>>(x, out);
}

// Round 14
// 42.023 us; speedup vs baseline: 1.3382x; 1.3382x over previous
//
#include <hip/hip_runtime.h>

#define NB 32
#define CC 3
#define HH 512
#define WW 512
#define KS 25
#define PAD 12
#define HT 8                  // output rows per block (full 512-wide strip)
#define LDSW2 268             // words per tile row: 6 halo + 256 + 6 halo (f16 pairs)

typedef __fp16 h2 __attribute__((ext_vector_type(2)));

#if __has_builtin(__builtin_amdgcn_fdot2)
#define FDOT2(a, b, c) __builtin_amdgcn_fdot2((a), (b), (c), false)
#else
#define FDOT2(a, b, c) ((float)(a).x * (float)(b).x + (float)(a).y * (float)(b).y + (c))
#endif

// normalized 1-D gaussian, sigma=9, K=25
__device__ constexpr float Wf[KS] = {
    0.02181520f, 0.02514307f, 0.02862302f, 0.03218484f, 0.03574584f,
    0.03921371f, 0.04249020f, 0.04547544f, 0.04807347f, 0.05019624f,
    0.05176967f, 0.05273727f, 0.05306384f, 0.05273727f, 0.05176967f,
    0.05019624f, 0.04807347f, 0.04547544f, 0.04249020f, 0.03921371f,
    0.03574584f, 0.03218484f, 0.02862302f, 0.02514307f, 0.02181520f};

__device__ constexpr float Wget(int t) {
    return (t >= 0 && t < KS) ? Wf[t] : 0.0f;
}

__device__ __forceinline__ float clamp01(float v) {
    return fminf(fmaxf(v, 0.0f), 1.0f);
}

// EDGE=false: strips 2..61, no bounds checks anywhere (94% of blocks).
// 128 threads; thread owns float4 cols [4t,4t+3] for ALL 8 rows.
// 16B loads double bytes-in-flight vs R11's float2 at same load-queue depth.
template<bool EDGE>
__device__ __forceinline__ void blur_body(const float* __restrict__ ibase,
                                          float* __restrict__ obase,
                                          int r0, int t, unsigned* tile16) {
    // zero halo words: per row, words 0..5 (cols -12..-1) and 262..267
    if (t < HT * 12) {
        int r = t / 12;
        int k = t - r * 12;
        tile16[r * LDSW2 + (k < 6 ? k : 256 + k)] = 0u;
    }

    const float* ip = ibase + t * 4;
    float acc[HT][4];
#pragma unroll
    for (int j = 0; j < HT; ++j)
#pragma unroll
        for (int c = 0; c < 4; ++c) acc[j][c] = 0.f;

#pragma unroll
    for (int k = 0; k < 16; ++k) {               // 16 row pairs = 32 rows
        int rr0 = r0 - PAD + 2 * k;
        int rr1 = rr0 + 1;
        float4 va = make_float4(0.f, 0.f, 0.f, 0.f);
        float4 vb = va;
        if (!EDGE || (rr0 >= 0 && rr0 < HH)) va = *(const float4*)(ip + (long)rr0 * WW);
        if (!EDGE || (rr1 >= 0 && rr1 < HH)) vb = *(const float4*)(ip + (long)rr1 * WW);
        h2 p0 = __builtin_amdgcn_cvt_pkrtz(va.x, vb.x);
        h2 p1 = __builtin_amdgcn_cvt_pkrtz(va.y, vb.y);
        h2 p2 = __builtin_amdgcn_cvt_pkrtz(va.z, vb.z);
        h2 p3 = __builtin_amdgcn_cvt_pkrtz(va.w, vb.w);
#pragma unroll
        for (int j = 0; j < HT; ++j) {
            const int t0 = 2 * k - j;            // tap of pair-lo (compile-time)
            if (t0 >= -1 && t0 <= 24) {
                const h2 wp = {(__fp16)Wget(t0), (__fp16)Wget(t0 + 1)};
                acc[j][0] = FDOT2(p0, wp, acc[j][0]);
                acc[j][1] = FDOT2(p1, wp, acc[j][1]);
                acc[j][2] = FDOT2(p2, wp, acc[j][2]);
                acc[j][3] = FDOT2(p3, wp, acc[j][3]);
            }
        }
    }
    // pack 4 cols -> 2 u32 words per row: words 2t, 2t+1 (+6 halo) = ds_write_b64
#pragma unroll
    for (int j = 0; j < HT; ++j) {
        h2 w0 = __builtin_amdgcn_cvt_pkrtz(acc[j][0], acc[j][1]);
        h2 w1 = __builtin_amdgcn_cvt_pkrtz(acc[j][2], acc[j][3]);
        uint2 wv = make_uint2(__builtin_bit_cast(unsigned, w0),
                              __builtin_bit_cast(unsigned, w1));
        *(uint2*)&tile16[j * LDSW2 + 6 + 2 * t] = wv;
    }

    __syncthreads();

    // ---- horizontal + clip: thread -> 8 consecutive outputs per iteration ----
    // Window = padded f16 [8g, 8g+31] = words [4g, 4g+15] = 4x ds_read_b128.
#pragma unroll
    for (int it = 0; it < 4; ++it) {             // 4 iters x 128 thr = 8 rows x 64 grp
        int f = it * 128 + t;
        int g = f & 63;                          // lanes -> adjacent col groups
        int row = f >> 6;                        // wave-uniform
        const unsigned* lp = &tile16[row * LDSW2 + 4 * g];
        h2 pa[16];
#pragma unroll
        for (int q = 0; q < 4; ++q) {
            uint4 c = *(const uint4*)(lp + 4 * q);
            pa[4 * q + 0] = __builtin_bit_cast(h2, c.x);
            pa[4 * q + 1] = __builtin_bit_cast(h2, c.y);
            pa[4 * q + 2] = __builtin_bit_cast(h2, c.z);
            pa[4 * q + 3] = __builtin_bit_cast(h2, c.w);
        }
        float res[8];
#pragma unroll
        for (int j = 0; j < 8; ++j) {
            float o = 0.f;
#pragma unroll
            for (int m = 0; m < 16; ++m) {
                const int t0 = 2 * m - j;        // compile-time
                if (t0 >= -1 && t0 <= 24) {
                    const h2 wp = {(__fp16)Wget(t0), (__fp16)Wget(t0 + 1)};
                    o = FDOT2(pa[m], wp, o);
                }
            }
            res[j] = clamp01(o);
        }
        float* op = obase + (long)(r0 + row) * WW + 8 * g;
        *(float4*)(op + 0) = make_float4(res[0], res[1], res[2], res[3]);
        *(float4*)(op + 4) = make_float4(res[4], res[5], res[6], res[7]);
    }
}

// (256,8) forced spills in R4/5 (WRITE 98->597MB). Allow up to 128 VGPR.
__global__ __launch_bounds__(128, 4) void gblur_fused(const float* __restrict__ x,
                                                      float* __restrict__ out) {
    __shared__ unsigned tile16[HT * LDSW2];      // 8,576 B

    int t = threadIdx.x;

    // ---- block mapping with bijective XCD swizzle (6144 % 8 == 0) ----
    int b = blockIdx.x;
    const int nwg = NB * CC * (HH / HT);         // 6144
    int per = nwg >> 3;
    int swz = (b & 7) * per + (b >> 3);
    int plane = swz >> 6;                        // 64 strips per plane
    int strip = swz & 63;
    int r0 = strip * HT;

    const float* ibase = x + (long)plane * (HH * WW);
    float*       obase = out + (long)plane * (HH * WW);

    // block-uniform edge test: window [r0-12, r0+19] inside [0,511]?
    if (r0 >= PAD && r0 <= HH - HT - PAD)
        blur_body<false>(ibase, obase, r0, t, tile16);
    else
        blur_body<true>(ibase, obase, r0, t, tile16);
}

extern "C" void kernel_launch(void* const* d_in, const int* in_sizes, int n_in,
                              void* d_out, int out_size, void* d_ws, size_t ws_size,
                              hipStream_t stream) {
    const float* x = (const float*)d_in[0];
    float* out = (float*)d_out;
    const int nwg = NB * CC * (HH / HT);         // 6144 blocks
    gblur_fused<<<nwg, 128, 0, stream>>>(x, out);
}

// Round 15
// 40.480 us; speedup vs baseline: 1.3893x; 1.0381x over previous
//
#include <hip/hip_runtime.h>

#define NB 32
#define CC 3
#define HH 512
#define WW 512
#define KS 25
#define PAD 12
#define SEG 64                // output rows per block (8 groups of 8)
#define NG (SEG / 8)
#define LDSW2 268             // words per tile row: 6 halo + 256 + 6 halo (f16 pairs)

typedef __fp16 h2 __attribute__((ext_vector_type(2)));

#if __has_builtin(__builtin_amdgcn_fdot2)
#define FDOT2(a, b, c) __builtin_amdgcn_fdot2((a), (b), (c), false)
#else
#define FDOT2(a, b, c) ((float)(a).x * (float)(b).x + (float)(a).y * (float)(b).y + (c))
#endif

// normalized 1-D gaussian, sigma=9, K=25
__device__ constexpr float Wf[KS] = {
    0.02181520f, 0.02514307f, 0.02862302f, 0.03218484f, 0.03574584f,
    0.03921371f, 0.04249020f, 0.04547544f, 0.04807347f, 0.05019624f,
    0.05176967f, 0.05273727f, 0.05306384f, 0.05273727f, 0.05176967f,
    0.05019624f, 0.04807347f, 0.04547544f, 0.04249020f, 0.03921371f,
    0.03574584f, 0.03218484f, 0.02862302f, 0.02514307f, 0.02181520f};

__device__ constexpr float Wget(int t) {
    return (t >= 0 && t < KS) ? Wf[t] : 0.0f;
}

__device__ __forceinline__ float clamp01(float v) {
    return fminf(fmaxf(v, 0.0f), 1.0f);
}

// Rolling-register vertical blur: each input row is loaded from global ONCE
// per block (read amplification 1.19x vs 4x for the 8-row-strip kernels;
// theory: the ~42us floor was L3 BW on 400MB of halo re-reads).
// Ring: 16 f16-pairs (32 rows) per column half, slots compile-time.
template<bool EDGE>
__device__ __forceinline__ void body(const float* __restrict__ ibase,
                                     float* __restrict__ obase,
                                     int r0, int t, unsigned* tile16) {
    // zero tile halo words once: rows 0..7, words 0..5 and 262..267
    if (t < 8 * 12) {
        int r = t / 12;
        int k = t - r * 12;
        tile16[r * LDSW2 + (k < 6 ? k : 256 + k)] = 0u;
    }

    const float* ip = ibase + t * 2;
    h2 ringx[16], ringy[16];

    // ---- prologue: pairs q=-6..9 = rows r0-12 .. r0+19, slot = q+6 ----
#pragma unroll
    for (int s = 0; s < 16; ++s) {
        int rr0 = r0 - PAD + 2 * s;
        int rr1 = rr0 + 1;
        float2 va = make_float2(0.f, 0.f), vb = va;
        if (!EDGE || (rr0 >= 0 && rr0 < HH)) va = *(const float2*)(ip + (long)rr0 * WW);
        if (!EDGE || (rr1 >= 0 && rr1 < HH)) vb = *(const float2*)(ip + (long)rr1 * WW);
        ringx[s] = __builtin_amdgcn_cvt_pkrtz(va.x, vb.x);
        ringy[s] = __builtin_amdgcn_cvt_pkrtz(va.y, vb.y);
    }

#pragma unroll
    for (int g = 0; g < NG; ++g) {
        // issue next-group loads early (hidden under this group's compute)
        float2 nva[4], nvb[4];
        if (g < NG - 1) {
#pragma unroll
            for (int i = 0; i < 4; ++i) {
                int rr0 = r0 + 8 * g + 20 + 2 * i;   // rows 8g+20..8g+27
                int rr1 = rr0 + 1;
                nva[i] = make_float2(0.f, 0.f);
                nvb[i] = make_float2(0.f, 0.f);
                if (!EDGE || (rr0 >= 0 && rr0 < HH)) nva[i] = *(const float2*)(ip + (long)rr0 * WW);
                if (!EDGE || (rr1 >= 0 && rr1 < HH)) nvb[i] = *(const float2*)(ip + (long)rr1 * WW);
            }
        }

        // ---- vertical: 8 output rows from ring (taps t0 = 2m - j, as R11) ----
        float accx[8], accy[8];
#pragma unroll
        for (int j = 0; j < 8; ++j) { accx[j] = 0.f; accy[j] = 0.f; }
#pragma unroll
        for (int m = 0; m < 16; ++m) {
            const int slot = (4 * g + m) & 15;       // compile-time
            h2 px = ringx[slot], py = ringy[slot];
#pragma unroll
            for (int j = 0; j < 8; ++j) {
                const int t0 = 2 * m - j;            // compile-time
                if (t0 >= -1 && t0 <= 24) {
                    const h2 wp = {(__fp16)Wget(t0), (__fp16)Wget(t0 + 1)};
                    accx[j] = FDOT2(px, wp, accx[j]);
                    accy[j] = FDOT2(py, wp, accy[j]);
                }
            }
        }
#pragma unroll
        for (int j = 0; j < 8; ++j) {
            h2 w = __builtin_amdgcn_cvt_pkrtz(accx[j], accy[j]);
            tile16[j * LDSW2 + 6 + t] = __builtin_bit_cast(unsigned, w);
        }

        // commit next-group pairs into oldest slots (read above at m=0..3)
        if (g < NG - 1) {
#pragma unroll
            for (int i = 0; i < 4; ++i) {
                const int slot = (4 * g + i) & 15;   // compile-time
                ringx[slot] = __builtin_amdgcn_cvt_pkrtz(nva[i].x, nvb[i].x);
                ringy[slot] = __builtin_amdgcn_cvt_pkrtz(nva[i].y, nvb[i].y);
            }
        }

        __syncthreads();                             // tile16 ready

        // ---- horizontal + clip: 8 rows (R11 code) ----
#pragma unroll
        for (int it = 0; it < 2; ++it) {
            int f = it * 256 + t;
            int c = f & 63;                          // col group
            int row = f >> 6;                        // wave-uniform
            const unsigned* lp = &tile16[row * LDSW2 + 4 * c];
            h2 pa[16];
#pragma unroll
            for (int q = 0; q < 4; ++q) {            // 4x ds_read_b128
                uint4 u = *(const uint4*)(lp + 4 * q);
                pa[4 * q + 0] = __builtin_bit_cast(h2, u.x);
                pa[4 * q + 1] = __builtin_bit_cast(h2, u.y);
                pa[4 * q + 2] = __builtin_bit_cast(h2, u.z);
                pa[4 * q + 3] = __builtin_bit_cast(h2, u.w);
            }
            float res[8];
#pragma unroll
            for (int j = 0; j < 8; ++j) {
                float o = 0.f;
#pragma unroll
                for (int m = 0; m < 16; ++m) {
                    const int t0 = 2 * m - j;        // compile-time
                    if (t0 >= -1 && t0 <= 24) {
                        const h2 wp = {(__fp16)Wget(t0), (__fp16)Wget(t0 + 1)};
                        o = FDOT2(pa[m], wp, o);
                    }
                }
                res[j] = clamp01(o);
            }
            float* op = obase + (long)(r0 + 8 * g + row) * WW + 8 * c;
            *(float4*)(op + 0) = make_float4(res[0], res[1], res[2], res[3]);
            *(float4*)(op + 4) = make_float4(res[4], res[5], res[6], res[7]);
        }

        __syncthreads();                             // tile16 reusable
    }
}

__global__ __launch_bounds__(256, 4) void gblur_fused(const float* __restrict__ x,
                                                      float* __restrict__ out) {
    __shared__ unsigned tile16[8 * LDSW2];           // 8,576 B

    int t = threadIdx.x;

    // ---- block mapping with bijective XCD swizzle (768 % 8 == 0) ----
    int b = blockIdx.x;
    const int nwg = NB * CC * (HH / SEG);            // 768
    int per = nwg >> 3;
    int swz = (b & 7) * per + (b >> 3);
    int plane = swz >> 3;                            // 8 segments per plane
    int seg = swz & 7;
    int r0 = seg * SEG;

    const float* ibase = x + (long)plane * (HH * WW);
    float*       obase = out + (long)plane * (HH * WW);

    // only first/last segments touch the vertical image edges
    if (seg == 0 || seg == (HH / SEG) - 1)
        body<true>(ibase, obase, r0, t, tile16);
    else
        body<false>(ibase, obase, r0, t, tile16);
}

extern "C" void kernel_launch(void* const* d_in, const int* in_sizes, int n_in,
                              void* d_out, int out_size, void* d_ws, size_t ws_size,
                              hipStream_t stream) {
    const float* x = (const float*)d_in[0];
    float* out = (float*)d_out;
    const int nwg = NB * CC * (HH / SEG);            // 768 blocks
    gblur_fused<<<nwg, 256, 0, stream>>>(x, out);
}